// Round 6
// baseline (526.285 us; speedup 1.0000x reference)
//
#include <hip/hip_runtime.h>
#include <hip/hip_bf16.h>
#include <stdint.h>

#define B_DIM 256
#define I_DIM 128
#define C_DIM 1024
#define N_DIM 512              // U*S
#define KC    (C_DIM * I_DIM)
#define WC    (N_DIM * I_DIM)
#define BI    (B_DIM * I_DIM)  // 32768: xc row stride per c

typedef __bf16 bf16;
typedef __attribute__((ext_vector_type(8))) __bf16 bf16x8;
typedef __attribute__((ext_vector_type(4))) float f32x4;

__device__ __forceinline__ void async_copy16(const void* g, void* l) {
  __builtin_amdgcn_global_load_lds(
      (const __attribute__((address_space(1))) uint32_t*)g,
      (__attribute__((address_space(3))) uint32_t*)l, 16, 0, 0);
}

// ---------------------------------------------------------------------------
// Kernel 1: xc[c][b][i] = (bf16) x[b][i][c].  c-major layout: per (c, b-range)
// A-slices are dense contiguous blocks.  64-MiB footprint (unchanged).
// ---------------------------------------------------------------------------
__global__ void __launch_bounds__(256)
transpose_cast(const float* __restrict__ x, bf16* __restrict__ xc) {
  __shared__ float tile[64][65];
  const int c0 = blockIdx.x * 64;
  const int i0 = blockIdx.y * 64;
  const int b  = blockIdx.z;
  const int t  = threadIdx.x;
  const int sub = t >> 4;
  const int cg  = t & 15;
  const float* xb = x + (size_t)b * (I_DIM * C_DIM);
#pragma unroll
  for (int r = 0; r < 4; ++r) {
    const int i = r * 16 + sub;
    const float4 v = *(const float4*)&xb[(size_t)(i0 + i) * C_DIM + c0 + cg * 4];
    tile[i][cg * 4 + 0] = v.x; tile[i][cg * 4 + 1] = v.y;
    tile[i][cg * 4 + 2] = v.z; tile[i][cg * 4 + 3] = v.w;
  }
  __syncthreads();
#pragma unroll
  for (int r = 0; r < 2; ++r) {
    const int c  = r * 32 + (t >> 3);
    const int ic = (t & 7) * 8;
    bf16x8 o;
#pragma unroll
    for (int k = 0; k < 8; ++k) o[k] = (bf16)tile[ic + k][c];
    *(bf16x8*)&xc[(size_t)(c0 + c) * BI + (size_t)b * I_DIM + i0 + ic] = o;
  }
}

// ---------------------------------------------------------------------------
// Kernel 2: streaming split-K GEMM — minimum staged volume.
// (Resubmission of the round-5 design: audited in-bounds on all streams;
//  prior "container failed twice" attributed to infra, not the kernel.)
// Grid 256 = 4 nb (Nt=128) x 64 c-chunks (16 c).  W slices are DISJOINT per
// block (read exactly once chip-wide, dense 64-KB/c blocks = whole 512-B
// rows -> perfect DRAM page streaming).  A is never staged to LDS: 8 waves
// m-split (32 b each) load their own bf16 fragments straight from xc into
// double-banked named registers (x4 dup across nb siblings, XCD-grouped;
// ~1 MB instantaneous working set per XCD L2 -> dedup likely).
// Per step (one c): 8 A-reg dwordx4 loads + 8 W global_load_lds per thread;
// ring-2 W (128 KB LDS); vmcnt(16) = previous step fully landed, current
// step fully in flight (FIFO: newest 16 = this step's ops).  W LDS swizzle:
// slot q ^= (n&15) on source and read -> ds_read_b128 2-way aliased (free).
// ---------------------------------------------------------------------------
__device__ __forceinline__ void stage_W(const float* __restrict__ W,
                                        float* Wsl, int tid, int c, int n0) {
  const float* base = W + (size_t)c * WC + (size_t)n0 * I_DIM;
#pragma unroll
  for (int p = 0; p < 8; ++p) {
    const int G = p * 512 + tid;      // 0..4095 16-B chunks
    const int n = G >> 5;             // 0..127
    const int s = G & 31;             // dest slot within row
    const int q = s ^ (n & 15);       // source chunk (involution)
    async_copy16(base + (size_t)n * I_DIM + q * 4, Wsl + (size_t)G * 4);
  }
}

__device__ __forceinline__ void load_A(const bf16* __restrict__ xc, int c,
                                       int wb, int l15, int lq,
                                       bf16x8 (&a)[2][4]) {
  const bf16* Ab = xc + (size_t)c * BI + (size_t)wb * I_DIM;
#pragma unroll
  for (int mt = 0; mt < 2; ++mt)
#pragma unroll
    for (int ks = 0; ks < 4; ++ks)
      a[mt][ks] = *(const bf16x8*)&Ab[(mt * 16 + l15) * I_DIM + ks * 32 + lq * 8];
}

__device__ __forceinline__ void compute_step(const bf16x8 (&a)[2][4],
    const float* Wsl, int l15, int lq, f32x4 (&acc)[2][8]) {
#pragma unroll
  for (int ks = 0; ks < 4; ++ks) {
#pragma unroll
    for (int nt = 0; nt < 8; ++nt) {
      const int n  = nt * 16 + l15;
      const int f  = l15;                       // n & 15
      const int qd = ks * 8 + lq * 2;
      const f32x4 lo = *(const f32x4*)&Wsl[n * I_DIM + ((qd)     ^ f) * 4];
      const f32x4 hi = *(const f32x4*)&Wsl[n * I_DIM + ((qd + 1) ^ f) * 4];
      bf16x8 bb;
      bb[0] = (bf16)lo[0]; bb[1] = (bf16)lo[1];
      bb[2] = (bf16)lo[2]; bb[3] = (bf16)lo[3];
      bb[4] = (bf16)hi[0]; bb[5] = (bf16)hi[1];
      bb[6] = (bf16)hi[2]; bb[7] = (bf16)hi[3];
#pragma unroll
      for (int mt = 0; mt < 2; ++mt)
        acc[mt][nt] = __builtin_amdgcn_mfma_f32_16x16x32_bf16(
            a[mt][ks], bb, acc[mt][nt], 0, 0, 0);
    }
  }
}

__global__ void __launch_bounds__(512, 2)
gemm_kernel(const bf16* __restrict__ xc, const float* __restrict__ W,
            float* __restrict__ sj) {
  __shared__ float Wl[2][128 * I_DIM];   // 2 x 64 KB = 128 KB
  const int tid  = threadIdx.x;
  const int lane = tid & 63;
  const int wave = tid >> 6;             // 0..7 -> owns b rows wave*32+:32
  const int wb   = wave * 32;
  const int l15  = lane & 15;
  const int lq   = lane >> 4;

  // bijective decode; the 4 nb-siblings of a chunk share XCD = g&7.
  const int g     = blockIdx.x;
  const int chunk = (g & 7) * 8 + ((g >> 3) & 7);   // 0..63
  const int nb    = g >> 6;                          // 0..3
  const int n0    = nb * 128;
  const int c0    = chunk * 16;

  f32x4  acc[2][8] = {};                 // 64 acc regs
  bf16x8 aA[2][4], aB[2][4];             // double-banked A fragments

  // prologue: step 0 fully issued (16 vmem ops; A first, then W-lds)
  load_A(xc, c0, wb, l15, lq, aA);
  stage_W(W, Wl[0], tid, c0, n0);

#pragma unroll 1
  for (int j = 0; j < 7; ++j) {          // pairs of steps (2j, 2j+1)
    const int t0 = 2 * j;
    load_A(xc, c0 + t0 + 1, wb, l15, lq, aB);
    stage_W(W, Wl[1], tid, c0 + t0 + 1, n0);
    asm volatile("s_waitcnt vmcnt(16)" ::: "memory");   // step t0 landed
    __builtin_amdgcn_sched_barrier(0);
    __builtin_amdgcn_s_barrier();
    compute_step(aA, Wl[0], l15, lq, acc);
    __builtin_amdgcn_s_barrier();        // Wl[0] reusable
    load_A(xc, c0 + t0 + 2, wb, l15, lq, aA);
    stage_W(W, Wl[0], tid, c0 + t0 + 2, n0);
    asm volatile("s_waitcnt vmcnt(16)" ::: "memory");   // step t0+1 landed
    __builtin_amdgcn_sched_barrier(0);
    __builtin_amdgcn_s_barrier();
    compute_step(aB, Wl[1], l15, lq, acc);
    __builtin_amdgcn_s_barrier();        // Wl[1] reusable
  }
  // steps 14, 15
  load_A(xc, c0 + 15, wb, l15, lq, aB);
  stage_W(W, Wl[1], tid, c0 + 15, n0);
  asm volatile("s_waitcnt vmcnt(16)" ::: "memory");
  __builtin_amdgcn_sched_barrier(0);
  __builtin_amdgcn_s_barrier();
  compute_step(aA, Wl[0], l15, lq, acc);
  asm volatile("s_waitcnt vmcnt(0)" ::: "memory");
  __builtin_amdgcn_sched_barrier(0);
  __builtin_amdgcn_s_barrier();
  compute_step(aB, Wl[1], l15, lq, acc);

  // epilogue: split-K partial -> sj (D layout: row = lq*4+r, col = l15)
#pragma unroll
  for (int mt = 0; mt < 2; ++mt) {
#pragma unroll
    for (int nt = 0; nt < 8; ++nt) {
      const int n = n0 + nt * 16 + l15;
#pragma unroll
      for (int r = 0; r < 4; ++r) {
        const int brow = wb + mt * 16 + lq * 4 + r;
        atomicAdd(&sj[(size_t)brow * N_DIM + n], acc[mt][nt][r]);
      }
    }
  }
}

// ---------------------------------------------------------------------------
// Kernel 3: squash.  per (b,s): msq = sum_u s^2 ; v = s * sqrt(msq)/(1+msq)
// ---------------------------------------------------------------------------
__global__ void __launch_bounds__(512)
squash_kernel(const float* __restrict__ sj, float* __restrict__ out) {
  __shared__ float sm[512];
  const int b = blockIdx.x;
  const int t = threadIdx.x;
  const float v = sj[(size_t)b * N_DIM + t];
  sm[t] = v * v;
  __syncthreads();
#pragma unroll
  for (int off = 256; off >= 16; off >>= 1) {
    if (t < off) sm[t] += sm[t + off];
    __syncthreads();
  }
  const float msq   = sm[t & 15];
  const float scale = sqrtf(msq) / (1.0f + msq);
  out[(size_t)b * N_DIM + t] = v * scale;
}

// ---------------------------------------------------------------------------
extern "C" void kernel_launch(void* const* d_in, const int* in_sizes, int n_in,
                              void* d_out, int out_size, void* d_ws, size_t ws_size,
                              hipStream_t stream) {
  const float* x = (const float*)d_in[0];   // (256,128,1024) fp32
  const float* W = (const float*)d_in[1];   // (1,1024,32,16,128) fp32
  float* out = (float*)d_out;               // (256,32,16,1) fp32

  bf16*  xc = (bf16*)d_ws;                                  // 64 MiB exactly
  float* sj = (float*)((char*)d_ws + (size_t)KC * B_DIM * sizeof(bf16));

  hipMemsetAsync(sj, 0, (size_t)B_DIM * N_DIM * sizeof(float), stream);
  transpose_cast<<<dim3(C_DIM / 64, I_DIM / 64, B_DIM), 256, 0, stream>>>(x, xc);
  gemm_kernel<<<dim3(256), 512, 0, stream>>>(xc, W, sj);
  squash_kernel<<<B_DIM, 512, 0, stream>>>(sj, out);
}

// Round 7
// 518.583 us; speedup vs baseline: 1.0149x; 1.0149x over previous
//
#include <hip/hip_runtime.h>
#include <hip/hip_bf16.h>
#include <stdint.h>

#define B_DIM 256
#define I_DIM 128
#define C_DIM 1024
#define N_DIM 512              // U*S
#define KC    (C_DIM * I_DIM)
#define WC    (N_DIM * I_DIM)
#define BI    (B_DIM * I_DIM)  // 32768: xc row stride per c

typedef __bf16 bf16;
typedef __attribute__((ext_vector_type(8))) __bf16 bf16x8;
typedef __attribute__((ext_vector_type(4))) float f32x4;

__device__ __forceinline__ void async_copy16(const void* g, void* l) {
  __builtin_amdgcn_global_load_lds(
      (const __attribute__((address_space(1))) uint32_t*)g,
      (__attribute__((address_space(3))) uint32_t*)l, 16, 0, 0);
}

// ---------------------------------------------------------------------------
// Kernel 1: xc[c][b][i] = (bf16) x[b][i][c].  c-major layout: per (c, b-range)
// A-slices are dense contiguous blocks.  64-MiB footprint (unchanged).
// ---------------------------------------------------------------------------
__global__ void __launch_bounds__(256)
transpose_cast(const float* __restrict__ x, bf16* __restrict__ xc) {
  __shared__ float tile[64][65];
  const int c0 = blockIdx.x * 64;
  const int i0 = blockIdx.y * 64;
  const int b  = blockIdx.z;
  const int t  = threadIdx.x;
  const int sub = t >> 4;
  const int cg  = t & 15;
  const float* xb = x + (size_t)b * (I_DIM * C_DIM);
#pragma unroll
  for (int r = 0; r < 4; ++r) {
    const int i = r * 16 + sub;
    const float4 v = *(const float4*)&xb[(size_t)(i0 + i) * C_DIM + c0 + cg * 4];
    tile[i][cg * 4 + 0] = v.x; tile[i][cg * 4 + 1] = v.y;
    tile[i][cg * 4 + 2] = v.z; tile[i][cg * 4 + 3] = v.w;
  }
  __syncthreads();
#pragma unroll
  for (int r = 0; r < 2; ++r) {
    const int c  = r * 32 + (t >> 3);
    const int ic = (t & 7) * 8;
    bf16x8 o;
#pragma unroll
    for (int k = 0; k < 8; ++k) o[k] = (bf16)tile[ic + k][c];
    *(bf16x8*)&xc[(size_t)(c0 + c) * BI + (size_t)b * I_DIM + i0 + ic] = o;
  }
}

// ---------------------------------------------------------------------------
// Kernel 2: streaming split-K GEMM — TLP-first variant.
// Round-6 counters: FETCH near-minimal, all pipes <25% -> latency-bound
// mega-block (1 block/CU, lockstep barriers).  Fix: halve the block so TWO
// independent blocks co-reside per CU (64-KB LDS each); one computes while
// the other stalls on vmcnt/barrier.
// Grid 512 = 8 nb (Nt=64) x 64 c-chunks (16 c).  W slices DISJOINT per block
// (read exactly once, dense whole 512-B rows).  A reg-loaded per wave
// (m-split 32 b), dup x8 across nb siblings, all on one XCD (decode below)
// with a 64-KB/step working set -> L2 dedup (proven by round-6 FETCH).
// Per step (one c): 8 A-reg loads + 4 W global_load_lds per thread; ring-2
// W slots; vmcnt(12) = previous step fully landed, current fully in flight.
// W LDS swizzle: slot q ^= (n&15) on source and read -> 2-way (free).
// ---------------------------------------------------------------------------
__device__ __forceinline__ void stage_W(const float* __restrict__ W,
                                        float* Wsl, int tid, int c, int n0) {
  const float* base = W + (size_t)c * WC + (size_t)n0 * I_DIM;
#pragma unroll
  for (int p = 0; p < 4; ++p) {
    const int G = p * 512 + tid;      // 0..2047 16-B chunks
    const int n = G >> 5;             // 0..63
    const int s = G & 31;             // dest slot within row
    const int q = s ^ (n & 15);       // source chunk (involution)
    async_copy16(base + (size_t)n * I_DIM + q * 4, Wsl + (size_t)G * 4);
  }
}

__device__ __forceinline__ void load_A(const bf16* __restrict__ xc, int c,
                                       int wb, int l15, int lq,
                                       bf16x8 (&a)[2][4]) {
  const bf16* Ab = xc + (size_t)c * BI + (size_t)wb * I_DIM;
#pragma unroll
  for (int mt = 0; mt < 2; ++mt)
#pragma unroll
    for (int ks = 0; ks < 4; ++ks)
      a[mt][ks] = *(const bf16x8*)&Ab[(mt * 16 + l15) * I_DIM + ks * 32 + lq * 8];
}

__device__ __forceinline__ void compute_step(const bf16x8 (&a)[2][4],
    const float* Wsl, int l15, int lq, f32x4 (&acc)[2][4]) {
#pragma unroll
  for (int ks = 0; ks < 4; ++ks) {
#pragma unroll
    for (int nt = 0; nt < 4; ++nt) {
      const int n  = nt * 16 + l15;
      const int f  = l15;                       // n & 15
      const int qd = ks * 8 + lq * 2;
      const f32x4 lo = *(const f32x4*)&Wsl[n * I_DIM + ((qd)     ^ f) * 4];
      const f32x4 hi = *(const f32x4*)&Wsl[n * I_DIM + ((qd + 1) ^ f) * 4];
      bf16x8 bb;
      bb[0] = (bf16)lo[0]; bb[1] = (bf16)lo[1];
      bb[2] = (bf16)lo[2]; bb[3] = (bf16)lo[3];
      bb[4] = (bf16)hi[0]; bb[5] = (bf16)hi[1];
      bb[6] = (bf16)hi[2]; bb[7] = (bf16)hi[3];
#pragma unroll
      for (int mt = 0; mt < 2; ++mt)
        acc[mt][nt] = __builtin_amdgcn_mfma_f32_16x16x32_bf16(
            a[mt][ks], bb, acc[mt][nt], 0, 0, 0);
    }
  }
}

__global__ void __launch_bounds__(512, 4)
gemm_kernel(const bf16* __restrict__ xc, const float* __restrict__ W,
            float* __restrict__ sj) {
  __shared__ float Wl[2][64 * I_DIM];    // 2 x 32 KB = 64 KB -> 2 blocks/CU
  const int tid  = threadIdx.x;
  const int lane = tid & 63;
  const int wave = tid >> 6;             // 0..7 -> owns b rows wave*32+:32
  const int wb   = wave * 32;
  const int l15  = lane & 15;
  const int lq   = lane >> 4;

  // bijective decode; the 8 nb-siblings of a chunk share XCD = g&7.
  const int g     = blockIdx.x;                      // 0..511
  const int nb    = (g >> 3) & 7;                    // 0..7
  const int chunk = (g & 7) * 8 + (g >> 6);          // 0..63
  const int n0    = nb * 64;
  const int c0    = chunk * 16;

  f32x4  acc[2][4] = {};                 // 32 acc regs
  bf16x8 aA[2][4], aB[2][4];             // double-banked A fragments

  // prologue: step 0 fully issued (12 vmem ops; A first, then W-lds)
  load_A(xc, c0, wb, l15, lq, aA);
  stage_W(W, Wl[0], tid, c0, n0);

#pragma unroll 1
  for (int j = 0; j < 7; ++j) {          // pairs of steps (2j, 2j+1)
    const int t0 = 2 * j;
    load_A(xc, c0 + t0 + 1, wb, l15, lq, aB);
    stage_W(W, Wl[1], tid, c0 + t0 + 1, n0);
    asm volatile("s_waitcnt vmcnt(12)" ::: "memory");   // step t0 landed
    __builtin_amdgcn_sched_barrier(0);
    __builtin_amdgcn_s_barrier();
    compute_step(aA, Wl[0], l15, lq, acc);
    __builtin_amdgcn_s_barrier();        // Wl[0] reusable
    load_A(xc, c0 + t0 + 2, wb, l15, lq, aA);
    stage_W(W, Wl[0], tid, c0 + t0 + 2, n0);
    asm volatile("s_waitcnt vmcnt(12)" ::: "memory");   // step t0+1 landed
    __builtin_amdgcn_sched_barrier(0);
    __builtin_amdgcn_s_barrier();
    compute_step(aB, Wl[1], l15, lq, acc);
    __builtin_amdgcn_s_barrier();        // Wl[1] reusable
  }
  // steps 14, 15
  load_A(xc, c0 + 15, wb, l15, lq, aB);
  stage_W(W, Wl[1], tid, c0 + 15, n0);
  asm volatile("s_waitcnt vmcnt(12)" ::: "memory");
  __builtin_amdgcn_sched_barrier(0);
  __builtin_amdgcn_s_barrier();
  compute_step(aA, Wl[0], l15, lq, acc);
  asm volatile("s_waitcnt vmcnt(0)" ::: "memory");
  __builtin_amdgcn_sched_barrier(0);
  __builtin_amdgcn_s_barrier();
  compute_step(aB, Wl[1], l15, lq, acc);

  // epilogue: split-K partial -> sj (D layout: row = lq*4+r, col = l15)
#pragma unroll
  for (int mt = 0; mt < 2; ++mt) {
#pragma unroll
    for (int nt = 0; nt < 4; ++nt) {
      const int n = n0 + nt * 16 + l15;
#pragma unroll
      for (int r = 0; r < 4; ++r) {
        const int brow = wb + mt * 16 + lq * 4 + r;
        atomicAdd(&sj[(size_t)brow * N_DIM + n], acc[mt][nt][r]);
      }
    }
  }
}

// ---------------------------------------------------------------------------
// Kernel 3: squash.  per (b,s): msq = sum_u s^2 ; v = s * sqrt(msq)/(1+msq)
// ---------------------------------------------------------------------------
__global__ void __launch_bounds__(512)
squash_kernel(const float* __restrict__ sj, float* __restrict__ out) {
  __shared__ float sm[512];
  const int b = blockIdx.x;
  const int t = threadIdx.x;
  const float v = sj[(size_t)b * N_DIM + t];
  sm[t] = v * v;
  __syncthreads();
#pragma unroll
  for (int off = 256; off >= 16; off >>= 1) {
    if (t < off) sm[t] += sm[t + off];
    __syncthreads();
  }
  const float msq   = sm[t & 15];
  const float scale = sqrtf(msq) / (1.0f + msq);
  out[(size_t)b * N_DIM + t] = v * scale;
}

// ---------------------------------------------------------------------------
extern "C" void kernel_launch(void* const* d_in, const int* in_sizes, int n_in,
                              void* d_out, int out_size, void* d_ws, size_t ws_size,
                              hipStream_t stream) {
  const float* x = (const float*)d_in[0];   // (256,128,1024) fp32
  const float* W = (const float*)d_in[1];   // (1,1024,32,16,128) fp32
  float* out = (float*)d_out;               // (256,32,16,1) fp32

  bf16*  xc = (bf16*)d_ws;                                  // 64 MiB exactly
  float* sj = (float*)((char*)d_ws + (size_t)KC * B_DIM * sizeof(bf16));

  hipMemsetAsync(sj, 0, (size_t)B_DIM * N_DIM * sizeof(float), stream);
  transpose_cast<<<dim3(C_DIM / 64, I_DIM / 64, B_DIM), 256, 0, stream>>>(x, xc);
  gemm_kernel<<<dim3(512), 512, 0, stream>>>(xc, W, sj);
  squash_kernel<<<B_DIM, 512, 0, stream>>>(sj, out);
}